// Round 1
// baseline (198.479 us; speedup 1.0000x reference)
//
#include <hip/hip_runtime.h>

// FraudDetectionModel: out = Linear(2,1)( chain_{l=0..31} [ tanh(h@W_l^T+b_l)*scale_l+shift_l ] (x) )
// B = 8388608 rows, each row an independent 2-dim recurrence -> embarrassingly parallel.
//
// Key algebraic folds (done once per block into LDS, exact up to f32 reassociation):
//   h_l = tanh(z_l)*s_l + t_l ;  z_{l+1} = W_{l+1} h_l + b_{l+1}
//     => W~_{l+1} = W_{l+1} diag(s_l),  b~_{l+1} = b_{l+1} + W_{l+1} t_l   (scale/shift gone)
//   tanh(z) = 1 - 2/(exp2(c*z)+1), c = 2*log2(e)  => fold c into W~, b~     (prescale gone)
//   final: w_out~ = w_out diag(s_31), b_out~ = b_out + w_out t_31
// Inner loop per row per layer: 4 FMA (affine) + 2x(exp2, add, rcp, fma) = 8 VALU + 4 trans.

constexpr int LAYERS = 32;
constexpr int BLOCK  = 256;
constexpr int R4     = 4;   // float4 x-loads per thread = 8 rows/thread

__device__ __forceinline__ float tanh_pre(float zs) {
    // zs = 2*log2(e) * z  (prescaled).  tanh(z) = 1 - 2*rcp(exp2(zs)+1)
    // zs -> +inf: exp2=inf, rcp=0, result 1.  zs -> -inf: exp2=0, rcp(1)=1, result -1.
#if __has_builtin(__builtin_amdgcn_exp2f)
    float e = __builtin_amdgcn_exp2f(zs);
#else
    float e = exp2f(zs);
#endif
#if __has_builtin(__builtin_amdgcn_rcpf)
    float r = __builtin_amdgcn_rcpf(e + 1.0f);
#else
    float r = 1.0f / (e + 1.0f);
#endif
    return fmaf(-2.0f, r, 1.0f);
}

__global__ __launch_bounds__(BLOCK) void fraud_fwd(
        const float* __restrict__ x,      // [B,2]
        const float* __restrict__ W,      // [32,2,2]
        const float* __restrict__ b,      // [32,2]
        const float* __restrict__ scale,  // [32,2]
        const float* __restrict__ shift,  // [32,2]
        const float* __restrict__ w_out,  // [1,2]
        const float* __restrict__ b_out,  // [1]
        float* __restrict__ out)          // [B,1]
{
    __shared__ float sP[LAYERS * 8];  // per layer: w00',w01',w10',w11',b0',b1',pad,pad (32B stride)
    __shared__ float sF[4];           // wo0', wo1', bo', pad

    const int t = threadIdx.x;
    const float c = 2.885390081777927f;  // 2*log2(e)

    if (t < LAYERS) {
        float w00 = W[t*4+0], w01 = W[t*4+1], w10 = W[t*4+2], w11 = W[t*4+3];
        float b0 = b[t*2+0], b1 = b[t*2+1];
        if (t > 0) {   // fold previous layer's scale/shift
            float s0  = scale[(t-1)*2+0], s1  = scale[(t-1)*2+1];
            float sh0 = shift[(t-1)*2+0], sh1 = shift[(t-1)*2+1];
            b0 += w00*sh0 + w01*sh1;
            b1 += w10*sh0 + w11*sh1;
            w00 *= s0; w01 *= s1; w10 *= s0; w11 *= s1;
        }
        sP[t*8+0] = w00*c; sP[t*8+1] = w01*c;
        sP[t*8+2] = w10*c; sP[t*8+3] = w11*c;
        sP[t*8+4] = b0 *c; sP[t*8+5] = b1 *c;
        sP[t*8+6] = 0.f;   sP[t*8+7] = 0.f;
    } else if (t == LAYERS) {
        float s0  = scale[31*2+0], s1  = scale[31*2+1];
        float sh0 = shift[31*2+0], sh1 = shift[31*2+1];
        float wo0 = w_out[0], wo1 = w_out[1];
        sF[0] = wo0*s0;
        sF[1] = wo1*s1;
        sF[2] = b_out[0] + wo0*sh0 + wo1*sh1;
        sF[3] = 0.f;
    }
    __syncthreads();

    const float4* __restrict__ xv = (const float4*)x;   // one float4 = 2 rows
    float2*       __restrict__ ov = (float2*)out;       // one float2 = 2 rows' outputs
    const int base4 = blockIdx.x * (BLOCK * R4) + t;    // block-interleaved -> every ld/st coalesced

    float hx[2*R4], hy[2*R4];
    #pragma unroll
    for (int i = 0; i < R4; ++i) {
        float4 a = xv[base4 + i*BLOCK];
        hx[2*i+0] = a.x; hy[2*i+0] = a.y;
        hx[2*i+1] = a.z; hy[2*i+1] = a.w;
    }

    for (int l = 0; l < LAYERS; ++l) {
        const float4 w  = *(const float4*)&sP[l*8];
        const float b0v = sP[l*8+4];
        const float b1v = sP[l*8+5];
        #pragma unroll
        for (int r = 0; r < 2*R4; ++r) {
            float z0 = fmaf(hx[r], w.x, fmaf(hy[r], w.y, b0v));
            float z1 = fmaf(hx[r], w.z, fmaf(hy[r], w.w, b1v));
            hx[r] = tanh_pre(z0);
            hy[r] = tanh_pre(z1);
        }
    }

    const float wo0 = sF[0], wo1 = sF[1], bo = sF[2];
    #pragma unroll
    for (int i = 0; i < R4; ++i) {
        float2 o;
        o.x = fmaf(hx[2*i+0], wo0, fmaf(hy[2*i+0], wo1, bo));
        o.y = fmaf(hx[2*i+1], wo0, fmaf(hy[2*i+1], wo1, bo));
        ov[base4 + i*BLOCK] = o;
    }
}

extern "C" void kernel_launch(void* const* d_in, const int* in_sizes, int n_in,
                              void* d_out, int out_size, void* d_ws, size_t ws_size,
                              hipStream_t stream) {
    const float* x     = (const float*)d_in[0];
    const float* W     = (const float*)d_in[1];
    const float* b     = (const float*)d_in[2];
    const float* scale = (const float*)d_in[3];
    const float* shift = (const float*)d_in[4];
    const float* w_out = (const float*)d_in[5];
    const float* b_out = (const float*)d_in[6];
    float* out = (float*)d_out;

    const int B = in_sizes[0] / 2;               // 8388608
    const int rows_per_block = BLOCK * R4 * 2;   // 2048
    const int blocks = B / rows_per_block;       // 4096 (B = 2^23 divides exactly)

    fraud_fwd<<<blocks, BLOCK, 0, stream>>>(x, W, b, scale, shift, w_out, b_out, out);
}

// Round 3
// 193.638 us; speedup vs baseline: 1.0250x; 1.0250x over previous
//
#include <hip/hip_runtime.h>

// FraudDetectionModel: out = Linear(2,1)( chain_{l=0..31} [ tanh(h@W_l^T+b_l)*scale_l+shift_l ] (x) )
// B = 8388608 independent rows of a 2-dim recurrence.
//
// Round-2 reformulation: track g = 1/(exp2(c*z)+1) instead of h (c = 2*log2(e)).
//   tanh(z) = 1 - 2g  is LINEAR in g -> folds into the next layer's affine:
//     h_l = s_l ⊙ (1-2g_l) + t_l
//     zs_{l+1} = c*z_{l+1} = C_{l+1} + M_{l+1} g_l,
//       M_{l+1} = -2c * W_{l+1} diag(s_l),  C_{l+1} = c*(b_{l+1} + W_{l+1}(s_l+t_l))
//   layer 0: M_0 = c*W_0, C_0 = c*b_0 (acts on raw x)
//   out = Co + Mo . g_31,  Mo = -2*w_out diag(s_31), Co = b_out + w_out(s_31+t_31)
// Pair-batched reciprocal per row: r = rcp(d0*d1); g0 = d1*r; g1 = d0*r.
//   Safe: d = exp2(zs)+1 >= 1, and zs0+zs1 < 128 for any plausible data
//   (needs both preactivations > 22 simultaneously; weights are 0.5*N(0,1) clipped).
// Inner loop per row per layer: 9 VALU + 3 trans (was 8 V + 4 T in round 1).

constexpr int LAYERS = 32;
constexpr int BLOCK  = 256;
constexpr int R4     = 4;   // float4 x-loads per thread = 8 rows/thread

__device__ __forceinline__ float fast_exp2(float x) {
#if __has_builtin(__builtin_amdgcn_exp2f)
    return __builtin_amdgcn_exp2f(x);
#else
    return exp2f(x);
#endif
}
__device__ __forceinline__ float fast_rcp(float x) {
#if __has_builtin(__builtin_amdgcn_rcpf)
    return __builtin_amdgcn_rcpf(x);
#else
    return 1.0f / x;
#endif
}

// One layer on one row: (ga,gb) -> (gx,gy) through zs = M*(ga,gb) + C.
__device__ __forceinline__ void layer_g(float ga, float gb,
                                        const float4 m, float C0, float C1,
                                        float& gx, float& gy) {
    float zs0 = fmaf(ga, m.x, fmaf(gb, m.y, C0));
    float zs1 = fmaf(ga, m.z, fmaf(gb, m.w, C1));
    float e0 = fast_exp2(zs0);
    float e1 = fast_exp2(zs1);
    float d0 = e0 + 1.0f;
    float d1 = e1 + 1.0f;
    float r  = fast_rcp(d0 * d1);
    gx = d1 * r;   // = 1/d0
    gy = d0 * r;   // = 1/d1
}

__global__ __launch_bounds__(BLOCK) void fraud_fwd(
        const float* __restrict__ x,      // [B,2]
        const float* __restrict__ W,      // [32,2,2]
        const float* __restrict__ b,      // [32,2]
        const float* __restrict__ scale,  // [32,2]
        const float* __restrict__ shift,  // [32,2]
        const float* __restrict__ w_out,  // [1,2]
        const float* __restrict__ b_out,  // [1]
        float* __restrict__ out)          // [B,1]
{
    __shared__ float sP[LAYERS * 8];  // per layer: m00,m01,m10,m11,C0,C1,pad,pad (32B stride)
    __shared__ float sF[4];           // Mo0, Mo1, Co, pad

    const int t = threadIdx.x;
    const float c = 2.885390081777927f;  // 2*log2(e)

    if (t < LAYERS) {
        float w00 = W[t*4+0], w01 = W[t*4+1], w10 = W[t*4+2], w11 = W[t*4+3];
        float b0 = b[t*2+0], b1 = b[t*2+1];
        float m00, m01, m10, m11, C0, C1;
        if (t > 0) {
            float s0 = scale[(t-1)*2+0], s1 = scale[(t-1)*2+1];
            float u0 = s0 + shift[(t-1)*2+0], u1 = s1 + shift[(t-1)*2+1];
            C0 = c * (b0 + w00*u0 + w01*u1);
            C1 = c * (b1 + w10*u0 + w11*u1);
            float k = -2.0f * c;
            m00 = k*w00*s0; m01 = k*w01*s1;
            m10 = k*w10*s0; m11 = k*w11*s1;
        } else {
            C0 = c*b0; C1 = c*b1;
            m00 = c*w00; m01 = c*w01; m10 = c*w10; m11 = c*w11;
        }
        sP[t*8+0] = m00; sP[t*8+1] = m01;
        sP[t*8+2] = m10; sP[t*8+3] = m11;
        sP[t*8+4] = C0;  sP[t*8+5] = C1;
        sP[t*8+6] = 0.f; sP[t*8+7] = 0.f;
    } else if (t == LAYERS) {
        float s0 = scale[31*2+0], s1 = scale[31*2+1];
        float u0 = s0 + shift[31*2+0], u1 = s1 + shift[31*2+1];
        float wo0 = w_out[0], wo1 = w_out[1];
        sF[0] = -2.0f * wo0 * s0;
        sF[1] = -2.0f * wo1 * s1;
        sF[2] = b_out[0] + wo0*u0 + wo1*u1;
        sF[3] = 0.f;
    }
    __syncthreads();

    const float4* __restrict__ xv = (const float4*)x;   // one float4 = 2 rows
    float2*       __restrict__ ov = (float2*)out;       // one float2 = 2 rows' outputs
    const int base4 = blockIdx.x * (BLOCK * R4) + t;    // block-interleaved -> coalesced

    float gx[2*R4], gy[2*R4];

    // Layer 0: from raw x.
    {
        const float4 m0 = *(const float4*)&sP[0];
        const float C0 = sP[4], C1 = sP[5];
        #pragma unroll
        for (int i = 0; i < R4; ++i) {
            float4 a = xv[base4 + i*BLOCK];
            layer_g(a.x, a.y, m0, C0, C1, gx[2*i+0], gy[2*i+0]);
            layer_g(a.z, a.w, m0, C0, C1, gx[2*i+1], gy[2*i+1]);
        }
    }

    // Layers 1..31, fully unrolled so ds_reads hoist and lgkmcnt stalls vanish.
    #pragma unroll
    for (int l = 1; l < LAYERS; ++l) {
        const float4 m  = *(const float4*)&sP[l*8];
        const float C0 = sP[l*8+4];
        const float C1 = sP[l*8+5];
        #pragma unroll
        for (int r = 0; r < 2*R4; ++r) {
            layer_g(gx[r], gy[r], m, C0, C1, gx[r], gy[r]);
        }
    }

    // Output fold: out = Co + Mo0*gx + Mo1*gy
    const float Mo0 = sF[0], Mo1 = sF[1], Co = sF[2];
    #pragma unroll
    for (int i = 0; i < R4; ++i) {
        float2 o;
        o.x = fmaf(gx[2*i+0], Mo0, fmaf(gy[2*i+0], Mo1, Co));
        o.y = fmaf(gx[2*i+1], Mo0, fmaf(gy[2*i+1], Mo1, Co));
        ov[base4 + i*BLOCK] = o;
    }
}

extern "C" void kernel_launch(void* const* d_in, const int* in_sizes, int n_in,
                              void* d_out, int out_size, void* d_ws, size_t ws_size,
                              hipStream_t stream) {
    const float* x     = (const float*)d_in[0];
    const float* W     = (const float*)d_in[1];
    const float* b     = (const float*)d_in[2];
    const float* scale = (const float*)d_in[3];
    const float* shift = (const float*)d_in[4];
    const float* w_out = (const float*)d_in[5];
    const float* b_out = (const float*)d_in[6];
    float* out = (float*)d_out;

    const int B = in_sizes[0] / 2;               // 8388608
    const int rows_per_block = BLOCK * R4 * 2;   // 2048
    const int blocks = B / rows_per_block;       // 4096

    fraud_fwd<<<blocks, BLOCK, 0, stream>>>(x, W, b, scale, shift, w_out, b_out, out);
}

// Round 5
// 188.227 us; speedup vs baseline: 1.0545x; 1.0287x over previous
//
#include <hip/hip_runtime.h>

// FraudDetectionModel: out = Linear(2,1)( chain_{l=0..31} [ tanh(h@W_l^T+b_l)*scale_l+shift_l ] (x) )
// B = 8388608 independent rows of a 2-dim recurrence.
//
// g-substitution (round 2): track g = 1/(exp2(c*z)+1), c = 2*log2(e).
//   tanh(z) = 1 - 2g is linear in g -> folds into next layer's affine:
//     M_{l+1} = -2c * W_{l+1} diag(s_l),  C_{l+1} = c*(b_{l+1} + W_{l+1}(s_l+t_l))
//   layer 0: M_0 = c*W_0, C_0 = c*b_0;  out = Co + Mo . g_31.
// Pair-batched rcp: r = rcp(d0*d1); gx = d1*r; gy = d0*r.
//   Overflow-safe: weights are 0.5*N(0,1) clipped -> |w| <~ 2.5, |h| <= |s|+|t| <~ 3.2
//   -> |z| <~ 17 -> zs0+zs1 < ~95 << 128. d >= 1 so no underflow.
// Cost/row-layer: 9 VALU (18 cyc) + 3 trans (~36 cyc @ measured ~12 cyc/trans) = ~54 cyc.
//
// Round-4 change: 16 rows/thread -> grid = 2048 blocks = 8 blocks/CU = 8 waves/SIMD,
// a single uniform residency round (no tail, no second occupancy wave), 2x ILP,
// per-layer LDS reads amortized over 16 rows. __launch_bounds__(256,8) pins VGPR<=64.

constexpr int LAYERS = 32;
constexpr int BLOCK  = 256;
constexpr int R4     = 8;   // float4 x-loads per thread = 16 rows/thread

__device__ __forceinline__ float fast_exp2(float x) {
#if __has_builtin(__builtin_amdgcn_exp2f)
    return __builtin_amdgcn_exp2f(x);
#else
    return exp2f(x);
#endif
}
__device__ __forceinline__ float fast_rcp(float x) {
#if __has_builtin(__builtin_amdgcn_rcpf)
    return __builtin_amdgcn_rcpf(x);
#else
    return 1.0f / x;
#endif
}

// One layer on one row: (ga,gb) -> (gx,gy) through zs = M*(ga,gb) + C.
__device__ __forceinline__ void layer_g(float ga, float gb,
                                        const float4 m, float C0, float C1,
                                        float& gx, float& gy) {
    float zs0 = fmaf(ga, m.x, fmaf(gb, m.y, C0));
    float zs1 = fmaf(ga, m.z, fmaf(gb, m.w, C1));
    float e0 = fast_exp2(zs0);
    float e1 = fast_exp2(zs1);
    float d0 = e0 + 1.0f;
    float d1 = e1 + 1.0f;
    float r  = fast_rcp(d0 * d1);
    gx = d1 * r;   // = 1/d0
    gy = d0 * r;   // = 1/d1
}

__global__ __launch_bounds__(BLOCK, 8) void fraud_fwd(
        const float* __restrict__ x,      // [B,2]
        const float* __restrict__ W,      // [32,2,2]
        const float* __restrict__ b,      // [32,2]
        const float* __restrict__ scale,  // [32,2]
        const float* __restrict__ shift,  // [32,2]
        const float* __restrict__ w_out,  // [1,2]
        const float* __restrict__ b_out,  // [1]
        float* __restrict__ out)          // [B,1]
{
    __shared__ float sP[LAYERS * 8];  // per layer: m00,m01,m10,m11,C0,C1,pad,pad (32B stride)
    __shared__ float sF[4];           // Mo0, Mo1, Co, pad

    const int t = threadIdx.x;
    const float c = 2.885390081777927f;  // 2*log2(e)

    if (t < LAYERS) {
        float w00 = W[t*4+0], w01 = W[t*4+1], w10 = W[t*4+2], w11 = W[t*4+3];
        float b0 = b[t*2+0], b1 = b[t*2+1];
        float m00, m01, m10, m11, C0, C1;
        if (t > 0) {
            float s0 = scale[(t-1)*2+0], s1 = scale[(t-1)*2+1];
            float u0 = s0 + shift[(t-1)*2+0], u1 = s1 + shift[(t-1)*2+1];
            C0 = c * (b0 + w00*u0 + w01*u1);
            C1 = c * (b1 + w10*u0 + w11*u1);
            float k = -2.0f * c;
            m00 = k*w00*s0; m01 = k*w01*s1;
            m10 = k*w10*s0; m11 = k*w11*s1;
        } else {
            C0 = c*b0; C1 = c*b1;
            m00 = c*w00; m01 = c*w01; m10 = c*w10; m11 = c*w11;
        }
        sP[t*8+0] = m00; sP[t*8+1] = m01;
        sP[t*8+2] = m10; sP[t*8+3] = m11;
        sP[t*8+4] = C0;  sP[t*8+5] = C1;
        sP[t*8+6] = 0.f; sP[t*8+7] = 0.f;
    } else if (t == LAYERS) {
        float s0 = scale[31*2+0], s1 = scale[31*2+1];
        float u0 = s0 + shift[31*2+0], u1 = s1 + shift[31*2+1];
        float wo0 = w_out[0], wo1 = w_out[1];
        sF[0] = -2.0f * wo0 * s0;
        sF[1] = -2.0f * wo1 * s1;
        sF[2] = b_out[0] + wo0*u0 + wo1*u1;
        sF[3] = 0.f;
    }
    __syncthreads();

    const float4* __restrict__ xv = (const float4*)x;   // one float4 = 2 rows
    float2*       __restrict__ ov = (float2*)out;       // one float2 = 2 rows' outputs
    const int base4 = blockIdx.x * (BLOCK * R4) + t;    // block-interleaved -> coalesced

    float gx[2*R4], gy[2*R4];

    // Layer 0: from raw x (loads issue back-to-back; latency paid once).
    {
        const float4 m0 = *(const float4*)&sP[0];
        const float C0 = sP[4], C1 = sP[5];
        #pragma unroll
        for (int i = 0; i < R4; ++i) {
            float4 a = xv[base4 + i*BLOCK];
            layer_g(a.x, a.y, m0, C0, C1, gx[2*i+0], gy[2*i+0]);
            layer_g(a.z, a.w, m0, C0, C1, gx[2*i+1], gy[2*i+1]);
        }
    }

    // Layers 1..31. unroll 4: enough to pipeline next-layer ds_reads under math,
    // small enough (~4KB) to stay I-cache-resident.
    #pragma unroll 4
    for (int l = 1; l < LAYERS; ++l) {
        const float4 m  = *(const float4*)&sP[l*8];
        const float C0 = sP[l*8+4];
        const float C1 = sP[l*8+5];
        #pragma unroll
        for (int r = 0; r < 2*R4; ++r) {
            layer_g(gx[r], gy[r], m, C0, C1, gx[r], gy[r]);
        }
    }

    // Output fold: out = Co + Mo0*gx + Mo1*gy
    const float Mo0 = sF[0], Mo1 = sF[1], Co = sF[2];
    #pragma unroll
    for (int i = 0; i < R4; ++i) {
        float2 o;
        o.x = fmaf(gx[2*i+0], Mo0, fmaf(gy[2*i+0], Mo1, Co));
        o.y = fmaf(gx[2*i+1], Mo0, fmaf(gy[2*i+1], Mo1, Co));
        ov[base4 + i*BLOCK] = o;
    }
}

extern "C" void kernel_launch(void* const* d_in, const int* in_sizes, int n_in,
                              void* d_out, int out_size, void* d_ws, size_t ws_size,
                              hipStream_t stream) {
    const float* x     = (const float*)d_in[0];
    const float* W     = (const float*)d_in[1];
    const float* b     = (const float*)d_in[2];
    const float* scale = (const float*)d_in[3];
    const float* shift = (const float*)d_in[4];
    const float* w_out = (const float*)d_in[5];
    const float* b_out = (const float*)d_in[6];
    float* out = (float*)d_out;

    const int B = in_sizes[0] / 2;               // 8388608
    const int rows_per_block = BLOCK * R4 * 2;   // 4096
    const int blocks = B / rows_per_block;       // 2048 = 8 blocks/CU, one uniform round

    fraud_fwd<<<blocks, BLOCK, 0, stream>>>(x, W, b, scale, shift, w_out, b_out, out);
}